// Round 3
// baseline (187.950 us; speedup 1.0000x reference)
//
#include <hip/hip_runtime.h>
#include <math.h>

#define KNN 16
#define NPTS 8192
#define PTCH 256
#define NPATCH 32
#define NBATCH 4
#define NQ 16            // queries per block (sixteenth of a patch)
#define SSTRIDE 130      // survivor slots/query (mean 64, +8sigma)
#define LAMBDA_T 64.0f   // target E[survivors]/query

// spatial grid
#define NC 16
#define NCELLS (NC * NC * NC)
#define GMIN -4.2f
#define ICS 1.9047619f   // 1 / 0.525 ; NC*0.525 = 8.4 spans [-4.2, 4.2]

// E[#points within distance s of a query at radius r], N iid N(0,I3). fp32.
// Heuristic only: exactness guaranteed by phase-B margin check + fallback.
__device__ __forceinline__ float lam_f(float r, float s)
{
    const float C     = 0.063493636f;    // (2*pi)^{-3/2}
    const float SQ2PI = 2.5066283f;
    const float IS2   = 0.70710678f;
    float a = fabsf(r - s), b = r + s;
    float amr = a - r;
    float coefA = amr * amr + 2.f - s * s;
    float I = 2.f * __expf(-0.5f * b * b) - coefA * __expf(-0.5f * a * a)
            + r * SQ2PI * (erff(b * IS2) - erff(a * IS2));
    float M = C * (3.14159265f / r) * I;
    if (s > r) {
        float u = s - r;
        M += 12.566371f * C * (1.2533141f * erff(u * IS2) - u * __expf(-0.5f * u * u));
    }
    return (float)NPTS * M;
}

// ---------- fp64 cyclic Jacobi 3x3 (verified R1-R7) ----------
__device__ __forceinline__ void jrot(double& app, double& aqq, double& apq,
                                     double& arp, double& arq,
                                     double& vp0, double& vq0,
                                     double& vp1, double& vq1,
                                     double& vp2, double& vq2)
{
    double g = apq;
    if (g == 0.0) return;
    double theta = (aqq - app) / (2.0 * g);
    double at = fabs(theta);
    double t = (at > 1.0e154) ? (0.5 / theta)
                              : (copysign(1.0, theta) / (at + sqrt(theta * theta + 1.0)));
    double c = 1.0 / sqrt(t * t + 1.0);
    double s = t * c;
    double tau = s / (1.0 + c);
    app -= t * g;
    aqq += t * g;
    apq = 0.0;
    double rp = arp, rq = arq;
    arp = rp - s * (rq + tau * rp);
    arq = rq + s * (rp - tau * rq);
    double p0 = vp0, q0 = vq0;
    vp0 = p0 - s * (q0 + tau * p0); vq0 = q0 + s * (p0 - tau * q0);
    double p1 = vp1, q1 = vq1;
    vp1 = p1 - s * (q1 + tau * p1); vq1 = q1 + s * (p1 - tau * q1);
    double p2 = vp2, q2 = vq2;
    vp2 = p2 - s * (q2 + tau * p2); vq2 = q2 + s * (p2 - tau * q2);
}

__device__ __forceinline__ void eig3(double a00, double a11, double a22,
                                     double a01, double a02, double a12,
                                     double& nx, double& ny, double& nz,
                                     double& lmin, double& lsum)
{
    double v00 = 1, v01 = 0, v02 = 0;
    double v10 = 0, v11 = 1, v12 = 0;
    double v20 = 0, v21 = 0, v22 = 1;
    double scale = fabs(a00) + fabs(a11) + fabs(a22) + fabs(a01) + fabs(a02) + fabs(a12);
    if (scale > 0.0) {
        for (int sweep = 0; sweep < 6; ++sweep) {
            double off = fabs(a01) + fabs(a02) + fabs(a12);
            if (off <= scale * 1e-15) break;
            jrot(a00, a11, a01, a02, a12, v00, v01, v10, v11, v20, v21);
            jrot(a00, a22, a02, a01, a12, v00, v02, v10, v12, v20, v22);
            jrot(a11, a22, a12, a01, a02, v01, v02, v11, v12, v21, v22);
        }
    }
    lsum = a00 + a11 + a22;
    lmin = a00; nx = v00; ny = v10; nz = v20;
    if (a11 < lmin) { lmin = a11; nx = v01; ny = v11; nz = v21; }
    if (a22 < lmin) { lmin = a22; nx = v02; ny = v12; nz = v22; }
}

// u32 key: (d2 float bits, low 13 mantissa bits cleared) | idx(13b). Ties -> lower idx.
__device__ __forceinline__ unsigned mkkey(float d2, unsigned idx) {
    return (__float_as_uint(d2) & 0xFFFFE000u) | idx;
}

// Caller guarantees key < L[15]. Sorted-ascending bubble (v_min/v_max pairs).
__device__ __forceinline__ void insert16(unsigned key, unsigned* L)
{
    L[KNN - 1] = key;
    #pragma unroll
    for (int m = KNN - 1; m >= 1; --m) {
        unsigned a = L[m - 1], b = L[m];
        L[m - 1] = min(a, b);
        L[m]     = max(a, b);
    }
}

// Snapshot-based butterfly merge of sorted 16-lists across lanes h = lane&3.
__device__ __forceinline__ void merge4(unsigned* L, int lane)
{
    #pragma unroll
    for (int step = 1; step <= 2; step <<= 1) {
        unsigned tmp[KNN];
        #pragma unroll
        for (int m = 0; m < KNN; ++m) tmp[m] = __shfl(L[m], lane ^ step, 64);
        for (int m = 0; m < KNN; ++m) {
            if (tmp[m] >= L[KNN - 1]) break;
            insert16(tmp[m], L);
        }
    }
}

__device__ __forceinline__ float rfl(float x) {
    return __int_as_float(__builtin_amdgcn_readfirstlane(__float_as_int(x)));
}
__device__ __forceinline__ unsigned mbcnt64(unsigned long long m) {
    return __builtin_amdgcn_mbcnt_hi((unsigned)(m >> 32),
           __builtin_amdgcn_mbcnt_lo((unsigned)m, 0u));
}

// ---------- grid build ----------
__device__ __forceinline__ int cidx(float v) {
    int i = (int)floorf((v - GMIN) * ICS);
    return min(max(i, 0), NC - 1);
}
__device__ __forceinline__ int cellOf(float x, float y, float z) {
    return (cidx(z) * NC + cidx(y)) * NC + cidx(x);
}

// One block per batch: zero out + histogram + scan + scatter, all in LDS.
#define BT 1024
__global__ void __launch_bounds__(1024)
build_kernel(const float* __restrict__ pts, float* __restrict__ out,
             unsigned* __restrict__ cellStart, float4* __restrict__ sorted)
{
    __shared__ unsigned hist[NCELLS];     // 16 KB; reused as cellPos after scan
    __shared__ unsigned part[BT];         // 4 KB
    const int b = blockIdx.x;
    const int t = threadIdx.x;
    if (b == 0 && t == 0) { out[0] = 0.0f; out[1] = 0.0f; }
    for (int i = t; i < NCELLS; i += BT) hist[i] = 0u;
    __syncthreads();
    const float* base = pts + (size_t)b * (NPTS * 3);
    float px[8], py[8], pz[8];
    int pc[8];
    #pragma unroll
    for (int k = 0; k < 8; ++k) {
        int i = k * BT + t;
        px[k] = base[i * 3 + 0];
        py[k] = base[i * 3 + 1];
        pz[k] = base[i * 3 + 2];
        pc[k] = cellOf(px[k], py[k], pz[k]);
        atomicAdd(&hist[pc[k]], 1u);
    }
    __syncthreads();
    // scan: thread t owns cells t*4 .. t*4+3
    unsigned loc[4], s = 0;
    #pragma unroll
    for (int i = 0; i < 4; ++i) { loc[i] = s; s += hist[t * 4 + i]; }
    part[t] = s;
    __syncthreads();
    for (int o = 1; o < BT; o <<= 1) {
        unsigned u = (t >= o) ? part[t - o] : 0u;
        __syncthreads();
        part[t] += u;
        __syncthreads();
    }
    unsigned basex = part[t] - s;   // exclusive prefix of this thread's 4-cell chunk
    unsigned* csb = cellStart + b * (NCELLS + 1);
    #pragma unroll
    for (int i = 0; i < 4; ++i) {
        unsigned e = basex + loc[i];
        csb[t * 4 + i] = e;
        hist[t * 4 + i] = e;        // becomes running cell position
    }
    if (t == BT - 1) csb[NCELLS] = basex + s;   // == NPTS
    __syncthreads();
    float4* sb = sorted + (size_t)b * NPTS;
    #pragma unroll
    for (int k = 0; k < 8; ++k) {
        int i = k * BT + t;
        unsigned slot = atomicAdd(&hist[pc[k]], 1u);
        float4 v;
        v.x = px[k]; v.y = py[k]; v.z = pz[k]; v.w = __uint_as_float((unsigned)i);
        sb[slot] = v;
    }
}

// Block = 256 threads, 16 queries; grid 2048.
// launch_bounds(256,4): VGPR cap 128 -- R2's (256,8) capped at 64 and spilled
// the Phase-B top-16 arrays to scratch (VGPR 32, WRITE_SIZE 10.4MB). At the
// natural ~40-48 VGPR the HW still co-resides 8 blocks/CU (32 waves, LDS 106KB).
__global__ void __launch_bounds__(256, 4)
spl_main(const float* __restrict__ pts, float* __restrict__ out,
         const unsigned* __restrict__ cellStart, const float4* __restrict__ sortedp)
{
    __shared__ float4 pbuf4[PTCH];                 // 4 KB own patch
    __shared__ unsigned survk[NQ * SSTRIDE];       // 8.3 KB survivor keys
    __shared__ unsigned cnts[NQ];
    __shared__ float gbuf[NQ];                     // gates (g^2)
    __shared__ double xbuf[NQ * 4];                // patch normal+sv
    // ~13.2 KB -> 8 blocks/CU

    const int t = threadIdx.x;
    const int w = t >> 6;
    const int lane = t & 63;
    const int p = blockIdx.x;
    const int sixt = blockIdx.y;
    const int b = blockIdx.z;

    const float* base = pts + (size_t)b * (NPTS * 3);
    const int qbase = p * PTCH + sixt * NQ;
    const unsigned* cs = cellStart + b * (NCELLS + 1);
    const float4* sp = sortedp + (size_t)b * NPTS;

    // Stage own patch into padded LDS.
    {
        const float* src = base + p * (PTCH * 3);
        float* dst = (float*)pbuf4;
        #pragma unroll
        for (int s = 0; s < 3; ++s) {
            int f = t + s * 256;
            int j = f / 3;
            int c = f - 3 * j;
            dst[j * 4 + c] = src[f];
        }
    }
    // Gates for this block's 16 queries (fp32 bisection, threads 0..15).
    if (t < NQ) {
        int qi = qbase + t;
        float x = base[qi * 3 + 0], y = base[qi * 3 + 1], z = base[qi * 3 + 2];
        float r = fmaxf(sqrtf(x * x + y * y + z * z), 0.01f);
        float lo = 0.f, hi = 12.f;
        #pragma unroll 1
        for (int it = 0; it < 16; ++it) {
            float mid = 0.5f * (lo + hi);
            if (lam_f(r, mid) < LAMBDA_T) lo = mid; else hi = mid;
        }
        gbuf[t] = hi * hi;
    }
    __syncthreads();

    // ---- Phase A: grid-gated filter, 4 serial queries per wave ----
    #pragma unroll 1
    for (int u = 0; u < 4; ++u) {
        const int q = w * 4 + u;
        float4 qv = pbuf4[sixt * NQ + q];
        float qx = rfl(qv.x), qy = rfl(qv.y), qz = rfl(qv.z);
        float g2 = rfl(gbuf[q]);
        float g = sqrtf(g2);
        int ixlo = cidx(qx - g), ixhi = cidx(qx + g);
        int iylo = cidx(qy - g), iyhi = cidx(qy + g);
        int izlo = cidx(qz - g), izhi = cidx(qz + g);
        int nx = ixhi - ixlo + 1;
        int ny = iyhi - iylo + 1;
        int nyz = ny * (izhi - izlo + 1);
        unsigned cnt = 0;                          // wave-uniform by construction
        unsigned sbase = (unsigned)q * SSTRIDE;
        #pragma unroll 1
        for (int r0 = 0; r0 < nyz; r0 += 64) {
            // lane-parallel preload of row bounds (x-adjacent cells contiguous)
            int r = r0 + lane;
            unsigned sB = 0, eB = 0;
            if (r < nyz) {
                int iz = izlo + r / ny;
                int iy = iylo + (r - (r / ny) * ny);
                int cb = (iz * NC + iy) * NC + ixlo;
                sB = cs[cb];
                eB = cs[cb + nx];
            }
            int rmax = min(nyz - r0, 64);
            #pragma unroll 2
            for (int rr = 0; rr < rmax; ++rr) {
                unsigned s0 = __shfl(sB, rr);
                unsigned e0 = __shfl(eB, rr);
                #pragma unroll 1
                for (unsigned jb = s0; jb < e0; jb += 64) {   // uniform trip count
                    unsigned j = jb + (unsigned)lane;
                    bool in = j < e0;
                    float4 c = sp[min(j, e0 - 1u)];
                    float dx = qx - c.x, dy = qy - c.y, dz = qz - c.z;
                    float d2 = dx * dx + dy * dy + dz * dz;   // reference-form d2
                    bool pass = in && (d2 < g2);
                    unsigned long long m = __ballot(pass);
                    if (m) {
                        if (pass) {
                            unsigned slot = min(cnt + mbcnt64(m), (unsigned)(SSTRIDE - 1));
                            survk[sbase + slot] = mkkey(d2, __float_as_uint(c.w));
                        }
                        cnt += (unsigned)__popcll(m);
                    }
                }
            }
        }
        if (lane == 0) cnts[q] = cnt;
    }
    __syncthreads();   // B1

    // ---- Phase B: 4 lanes per query ----
    const int qq = lane >> 2;            // query 0..15
    const int h = lane & 3;              // sub-lane
    const int myq = qq;
    float4 qv = pbuf4[sixt * NQ + myq];
    const float pqx = qv.x, pqy = qv.y, pqz = qv.z;

    double ngx = 0, ngy = 0, ngz = 0, svg = 0;

    if (w == 0) {
        // Global top-16: split survivor keys 4 ways, gated bubble, butterfly merge.
        unsigned gl[KNN];
        #pragma unroll
        for (int m = 0; m < KNN; ++m) gl[m] = 0xFFFFFFFFu;
        unsigned cnt = cnts[myq];
        bool valid = (cnt >= KNN) && (cnt <= SSTRIDE);
        if (valid) {
            unsigned share = (cnt + 3) >> 2;
            unsigned m0 = h * share;
            unsigned m1 = min(m0 + share, cnt);
            #pragma unroll 1
            for (unsigned m = m0; m < m1; ++m) {
                unsigned k = survk[myq * SSTRIDE + m];
                if (k < gl[KNN - 1]) insert16(k, gl);
            }
        }
        merge4(gl, lane);
        if (valid) {
            // margin check: all filtered-out points provably outside 16th bucket
            float g = gbuf[myq];
            float upper = __uint_as_float((gl[KNN - 1] & 0xFFFFE000u) + 0x2000u);
            valid = (upper < g * 0.999f - 1e-5f);
        }
        if (__any((h == 0 && !valid) ? 1 : 0)) {
            if (h == 0 && !valid) {   // exact fallback (P ~ 1e-9/query)
                #pragma unroll
                for (int m = 0; m < KNN; ++m) gl[m] = 0xFFFFFFFFu;
                #pragma unroll 1
                for (int i = 0; i < NPTS; ++i) {
                    float cx = base[i * 3 + 0];
                    float cy = base[i * 3 + 1];
                    float cz = base[i * 3 + 2];
                    float dx = pqx - cx, dy = pqy - cy, dz = pqz - cz;
                    float d2 = dx * dx + dy * dy + dz * dz;
                    unsigned k = mkkey(d2, (unsigned)i);
                    if (k < gl[KNN - 1]) insert16(k, gl);
                }
            }
        }
        if (h == 0) {
            double c00 = 0, c11 = 0, c22 = 0, c01 = 0, c02 = 0, c12 = 0;
            const double qxd = pqx, qyd = pqy, qzd = pqz;
            #pragma unroll
            for (int m = 0; m < KNN; ++m) {
                int idx = (int)(gl[m] & 0x1FFFu);
                double dx = (double)base[idx * 3 + 0] - qxd;
                double dy = (double)base[idx * 3 + 1] - qyd;
                double dz = (double)base[idx * 3 + 2] - qzd;
                c00 += dx * dx; c11 += dy * dy; c22 += dz * dz;
                c01 += dx * dy; c02 += dx * dz; c12 += dy * dz;
            }
            double lmin, lsum;
            eig3(c00, c11, c22, c01, c02, c12, ngx, ngy, ngz, lmin, lsum);
            svg = lmin / lsum;
        }
    } else if (w == 1) {
        // Patch kNN: 4 lanes x 64 patch points, gated bubble, butterfly merge.
        unsigned pl[KNN];
        #pragma unroll
        for (int m = 0; m < KNN; ++m) pl[m] = 0xFFFFFFFFu;
        const int j0 = h * 64;
        #pragma unroll 1
        for (int j = j0; j < j0 + 64; ++j) {
            float4 c = pbuf4[j];
            float dx = pqx - c.x, dy = pqy - c.y, dz = pqz - c.z;
            float d2 = dx * dx + dy * dy + dz * dz;
            unsigned k = mkkey(d2, (unsigned)j);
            if (k < pl[KNN - 1]) insert16(k, pl);
        }
        merge4(pl, lane);
        if (h == 0) {
            double c00 = 0, c11 = 0, c22 = 0, c01 = 0, c02 = 0, c12 = 0;
            const double qxd = pqx, qyd = pqy, qzd = pqz;
            #pragma unroll
            for (int m = 0; m < KNN; ++m) {
                int idx = (int)(pl[m] & 0x1FFFu);
                float4 cpt = pbuf4[idx];
                double dx = (double)cpt.x - qxd;
                double dy = (double)cpt.y - qyd;
                double dz = (double)cpt.z - qzd;
                c00 += dx * dx; c11 += dy * dy; c22 += dz * dz;
                c01 += dx * dy; c02 += dx * dz; c12 += dy * dz;
            }
            double nx, ny, nz, lmin, lsum;
            eig3(c00, c11, c22, c01, c02, c12, nx, ny, nz, lmin, lsum);
            xbuf[myq * 4 + 0] = nx;
            xbuf[myq * 4 + 1] = ny;
            xbuf[myq * 4 + 2] = nz;
            xbuf[myq * 4 + 3] = lmin / lsum;
        }
    }
    __syncthreads();   // B2

    if (w == 0) {
        double ln = 0.0, lsv = 0.0;
        if (h == 0) {
            double npx = xbuf[myq * 4 + 0];
            double npy = xbuf[myq * 4 + 1];
            double npz = xbuf[myq * 4 + 2];
            double svp = xbuf[myq * 4 + 3];
            double dx = fabs(npx) - fabs(ngx);
            double dy = fabs(npy) - fabs(ngy);
            double dz = fabs(npz) - fabs(ngz);
            ln  = sqrt(dx * dx + dy * dy + dz * dz);
            double ds = svp - svg;
            lsv = ds * ds;
        }
        #pragma unroll
        for (int o = 32; o > 0; o >>= 1) {
            ln  += __shfl_down(ln, o);
            lsv += __shfl_down(lsv, o);
        }
        if (lane == 0) {
            const double inv = 1.0 / (double)(NBATCH * NPTS);
            atomicAdd(&out[0], (float)(ln * inv));
            atomicAdd(&out[1], (float)(lsv * inv));
        }
    }
}

extern "C" void kernel_launch(void* const* d_in, const int* in_sizes, int n_in,
                              void* d_out, int out_size, void* d_ws, size_t ws_size,
                              hipStream_t stream)
{
    const float* pts = (const float*)d_in[0];
    float* out = (float*)d_out;

    // workspace carve-up (16B-aligned): ~590 KB total
    unsigned char* ws = (unsigned char*)d_ws;
    unsigned* cellStart = (unsigned*)(ws);            // 4*4097*4 = 65552 B
    float4*   sorted    = (float4*)  (ws + 65552);    // 4*8192*16 = 524288 B

    hipLaunchKernelGGL(build_kernel, dim3(NBATCH), dim3(BT), 0, stream,
                       pts, out, cellStart, sorted);
    dim3 grid(NPATCH, 16, NBATCH);
    hipLaunchKernelGGL(spl_main, grid, dim3(256), 0, stream, pts, out, cellStart, sorted);
}

// Round 4
// 160.980 us; speedup vs baseline: 1.1675x; 1.1675x over previous
//
#include <hip/hip_runtime.h>
#include <math.h>

#define KNN 16
#define NPTS 8192
#define PTCH 256
#define NPATCH 32
#define NBATCH 4
#define NQ 32            // queries per block (eighth patch)
#define SSTRIDE 130      // survivor slots/query (mean 64, +8sigma)
#define LAMBDA_T 64.0f   // target E[survivors]/query

// spatial grid
#define NC 16
#define NCELLS (NC * NC * NC)
#define GMIN -4.2f
#define ICS 1.9047619f   // 1 / 0.525 ; NC*0.525 = 8.4 spans [-4.2, 4.2]

// E[#points within distance s of a query at radius r], N iid N(0,I3). fp32.
// Heuristic only: exactness guaranteed by phase-B margin check + fallback.
__device__ __forceinline__ float lam_f(float r, float s)
{
    const float C     = 0.063493636f;    // (2*pi)^{-3/2}
    const float SQ2PI = 2.5066283f;
    const float IS2   = 0.70710678f;
    float a = fabsf(r - s), b = r + s;
    float amr = a - r;
    float coefA = amr * amr + 2.f - s * s;
    float I = 2.f * __expf(-0.5f * b * b) - coefA * __expf(-0.5f * a * a)
            + r * SQ2PI * (erff(b * IS2) - erff(a * IS2));
    float M = C * (3.14159265f / r) * I;
    if (s > r) {
        float u = s - r;
        M += 12.566371f * C * (1.2533141f * erff(u * IS2) - u * __expf(-0.5f * u * u));
    }
    return (float)NPTS * M;
}

// ---------- fp64 cyclic Jacobi 3x3 (verified R1-R7) ----------
__device__ __forceinline__ void jrot(double& app, double& aqq, double& apq,
                                     double& arp, double& arq,
                                     double& vp0, double& vq0,
                                     double& vp1, double& vq1,
                                     double& vp2, double& vq2)
{
    double g = apq;
    if (g == 0.0) return;
    double theta = (aqq - app) / (2.0 * g);
    double at = fabs(theta);
    double t = (at > 1.0e154) ? (0.5 / theta)
                              : (copysign(1.0, theta) / (at + sqrt(theta * theta + 1.0)));
    double c = 1.0 / sqrt(t * t + 1.0);
    double s = t * c;
    double tau = s / (1.0 + c);
    app -= t * g;
    aqq += t * g;
    apq = 0.0;
    double rp = arp, rq = arq;
    arp = rp - s * (rq + tau * rp);
    arq = rq + s * (rp - tau * rq);
    double p0 = vp0, q0 = vq0;
    vp0 = p0 - s * (q0 + tau * p0); vq0 = q0 + s * (p0 - tau * q0);
    double p1 = vp1, q1 = vq1;
    vp1 = p1 - s * (q1 + tau * p1); vq1 = q1 + s * (p1 - tau * q1);
    double p2 = vp2, q2 = vq2;
    vp2 = p2 - s * (q2 + tau * p2); vq2 = q2 + s * (p2 - tau * q2);
}

__device__ __forceinline__ void eig3(double a00, double a11, double a22,
                                     double a01, double a02, double a12,
                                     double& nx, double& ny, double& nz,
                                     double& lmin, double& lsum)
{
    double v00 = 1, v01 = 0, v02 = 0;
    double v10 = 0, v11 = 1, v12 = 0;
    double v20 = 0, v21 = 0, v22 = 1;
    double scale = fabs(a00) + fabs(a11) + fabs(a22) + fabs(a01) + fabs(a02) + fabs(a12);
    if (scale > 0.0) {
        for (int sweep = 0; sweep < 6; ++sweep) {
            double off = fabs(a01) + fabs(a02) + fabs(a12);
            if (off <= scale * 1e-15) break;
            jrot(a00, a11, a01, a02, a12, v00, v01, v10, v11, v20, v21);
            jrot(a00, a22, a02, a01, a12, v00, v02, v10, v12, v20, v22);
            jrot(a11, a22, a12, a01, a02, v01, v02, v11, v12, v21, v22);
        }
    }
    lsum = a00 + a11 + a22;
    lmin = a00; nx = v00; ny = v10; nz = v20;
    if (a11 < lmin) { lmin = a11; nx = v01; ny = v11; nz = v21; }
    if (a22 < lmin) { lmin = a22; nx = v02; ny = v12; nz = v22; }
}

// u32 key: (d2 float bits, low 13 mantissa bits cleared) | idx(13b). Ties -> lower idx.
__device__ __forceinline__ unsigned mkkey(float d2, unsigned idx) {
    return (__float_as_uint(d2) & 0xFFFFE000u) | idx;
}

// Caller guarantees key < L[15]. Sorted-ascending bubble (v_min/v_max pairs).
__device__ __forceinline__ void insert16(unsigned key, unsigned* L)
{
    L[KNN - 1] = key;
    #pragma unroll
    for (int m = KNN - 1; m >= 1; --m) {
        unsigned a = L[m - 1], b = L[m];
        L[m - 1] = min(a, b);
        L[m]     = max(a, b);
    }
}

// Snapshot-based butterfly merge of sorted 16-lists across lanes h = lane&3.
__device__ __forceinline__ void merge4(unsigned* L, int lane)
{
    #pragma unroll
    for (int step = 1; step <= 2; step <<= 1) {
        unsigned tmp[KNN];
        #pragma unroll
        for (int m = 0; m < KNN; ++m) tmp[m] = __shfl(L[m], lane ^ step, 64);
        for (int m = 0; m < KNN; ++m) {
            if (tmp[m] >= L[KNN - 1]) break;
            insert16(tmp[m], L);
        }
    }
}

__device__ __forceinline__ float rfl(float x) {
    return __int_as_float(__builtin_amdgcn_readfirstlane(__float_as_int(x)));
}
__device__ __forceinline__ unsigned mbcnt64(unsigned long long m) {
    return __builtin_amdgcn_mbcnt_hi((unsigned)(m >> 32),
           __builtin_amdgcn_mbcnt_lo((unsigned)m, 0u));
}

// ---------- grid build ----------
__device__ __forceinline__ int cidx(float v) {
    int i = (int)floorf((v - GMIN) * ICS);
    return min(max(i, 0), NC - 1);
}
__device__ __forceinline__ int cellOf(float x, float y, float z) {
    return (cidx(z) * NC + cidx(y)) * NC + cidx(x);
}

// One block per batch: zero out + histogram + scan + scatter, all in LDS.
#define BT 1024
__global__ void __launch_bounds__(1024)
build_kernel(const float* __restrict__ pts, float* __restrict__ out,
             unsigned* __restrict__ cellStart, float4* __restrict__ sorted)
{
    __shared__ unsigned hist[NCELLS];     // 16 KB; reused as cellPos after scan
    __shared__ unsigned part[BT];         // 4 KB
    const int b = blockIdx.x;
    const int t = threadIdx.x;
    if (b == 0 && t == 0) { out[0] = 0.0f; out[1] = 0.0f; }
    for (int i = t; i < NCELLS; i += BT) hist[i] = 0u;
    __syncthreads();
    const float* base = pts + (size_t)b * (NPTS * 3);
    float px[8], py[8], pz[8];
    int pc[8];
    #pragma unroll
    for (int k = 0; k < 8; ++k) {
        int i = k * BT + t;
        px[k] = base[i * 3 + 0];
        py[k] = base[i * 3 + 1];
        pz[k] = base[i * 3 + 2];
        pc[k] = cellOf(px[k], py[k], pz[k]);
        atomicAdd(&hist[pc[k]], 1u);
    }
    __syncthreads();
    // scan: thread t owns cells t*4 .. t*4+3
    unsigned loc[4], s = 0;
    #pragma unroll
    for (int i = 0; i < 4; ++i) { loc[i] = s; s += hist[t * 4 + i]; }
    part[t] = s;
    __syncthreads();
    for (int o = 1; o < BT; o <<= 1) {
        unsigned u = (t >= o) ? part[t - o] : 0u;
        __syncthreads();
        part[t] += u;
        __syncthreads();
    }
    unsigned basex = part[t] - s;   // exclusive prefix of this thread's 4-cell chunk
    unsigned* csb = cellStart + b * (NCELLS + 1);
    #pragma unroll
    for (int i = 0; i < 4; ++i) {
        unsigned e = basex + loc[i];
        csb[t * 4 + i] = e;
        hist[t * 4 + i] = e;        // becomes running cell position
    }
    if (t == BT - 1) csb[NCELLS] = basex + s;   // == NPTS
    __syncthreads();
    float4* sb = sorted + (size_t)b * NPTS;
    #pragma unroll
    for (int k = 0; k < 8; ++k) {
        int i = k * BT + t;
        unsigned slot = atomicAdd(&hist[pc[k]], 1u);
        float4 v;
        v.x = px[k]; v.y = py[k]; v.z = pz[k]; v.w = __uint_as_float((unsigned)i);
        sb[slot] = v;
    }
}

// Block = 256 threads, 32 queries (eighth patch); grid 1024 (R1 structure:
// all 4 waves active in BOTH phases -- R2/R3's idle Phase-B waves regressed).
// Phase A: per wave, 8 serial queries; cell-rows are COMPACTED into a dense
//          64-wide work queue (prefix-sum + per-lane binary search) so every
//          memory round processes 64 real candidates (~3-5 rounds/query vs
//          ~15-25 sparse row rounds before).
// Phase B: waves0/1 = global top-16 (4 lanes/query); waves2/3 = patch kNN.
__global__ void __launch_bounds__(256, 4)
spl_main(const float* __restrict__ pts, float* __restrict__ out,
         const unsigned* __restrict__ cellStart, const float4* __restrict__ sortedp)
{
    __shared__ float4 pbuf4[PTCH];                 // 4 KB own patch
    __shared__ unsigned survk[NQ * SSTRIDE];       // 16.6 KB survivor keys
    __shared__ unsigned cnts[NQ];
    __shared__ float gbuf[NQ];                     // gates (g^2)
    __shared__ double xbuf[NQ * 4];                // patch normal+sv
    __shared__ double rb[4];                       // partials
    // ~22 KB

    const int t = threadIdx.x;
    const int w = t >> 6;
    const int lane = t & 63;
    const int p = blockIdx.x;
    const int eighth = blockIdx.y;
    const int b = blockIdx.z;

    const float* base = pts + (size_t)b * (NPTS * 3);
    const int qbase = p * PTCH + eighth * NQ;
    const unsigned* cs = cellStart + b * (NCELLS + 1);
    const float4* sp = sortedp + (size_t)b * NPTS;

    // Stage own patch into padded LDS.
    {
        const float* src = base + p * (PTCH * 3);
        float* dst = (float*)pbuf4;
        #pragma unroll
        for (int s = 0; s < 3; ++s) {
            int f = t + s * 256;
            int j = f / 3;
            int c = f - 3 * j;
            dst[j * 4 + c] = src[f];
        }
    }
    // Gates for this block's 32 queries (fp32 bisection, threads 0..31).
    if (t < NQ) {
        int qi = qbase + t;
        float x = base[qi * 3 + 0], y = base[qi * 3 + 1], z = base[qi * 3 + 2];
        float r = fmaxf(sqrtf(x * x + y * y + z * z), 0.01f);
        float lo = 0.f, hi = 12.f;
        #pragma unroll 1
        for (int it = 0; it < 16; ++it) {
            float mid = 0.5f * (lo + hi);
            if (lam_f(r, mid) < LAMBDA_T) lo = mid; else hi = mid;
        }
        gbuf[t] = hi * hi;
    }
    __syncthreads();

    // ---- Phase A: grid-gated compacted filter, 8 serial queries per wave ----
    #pragma unroll 1
    for (int u = 0; u < 8; ++u) {
        const int q = w * 8 + u;
        float4 qv = pbuf4[eighth * NQ + q];
        float qx = rfl(qv.x), qy = rfl(qv.y), qz = rfl(qv.z);
        float g2 = rfl(gbuf[q]);
        float g = sqrtf(g2);
        int ixlo = cidx(qx - g), ixhi = cidx(qx + g);
        int iylo = cidx(qy - g), iyhi = cidx(qy + g);
        int izlo = cidx(qz - g), izhi = cidx(qz + g);
        int nx = ixhi - ixlo + 1;
        int ny = iyhi - iylo + 1;
        int nyz = ny * (izhi - izlo + 1);
        unsigned cnt = 0;                          // wave-uniform by construction
        unsigned sbase = (unsigned)q * SSTRIDE;
        #pragma unroll 1
        for (int r0 = 0; r0 < nyz; r0 += 64) {
            // lane r owns one cell-row (nx contiguous cells)
            int r = r0 + lane;
            unsigned sB = 0, len = 0;
            if (r < nyz) {
                int iz = izlo + r / ny;
                int iy = iylo + (r - (r / ny) * ny);
                int cb = (iz * NC + iy) * NC + ixlo;
                sB = cs[cb];
                len = cs[cb + nx] - sB;
            }
            // wave prefix-sum of row lengths -> dense work queue of T candidates
            unsigned pre = len;
            #pragma unroll
            for (int o = 1; o < 64; o <<= 1) {
                unsigned v = __shfl_up(pre, o, 64);
                if (lane >= o) pre += v;
            }
            unsigned T = __shfl(pre, 63, 64);
            unsigned ex = pre - len;               // exclusive prefix (ex[0]==0)
            unsigned dif = sB - ex;                // row start minus queue offset
            #pragma unroll 1
            for (unsigned i0 = 0; i0 < T; i0 += 64) {
                unsigned pos = i0 + (unsigned)lane;
                // rightmost j with ex[j] <= pos (ex non-decreasing)
                int j = 0;
                #pragma unroll
                for (int st = 32; st >= 1; st >>= 1) {
                    int jj = j + st;                       // <= 63 always
                    unsigned v = __shfl(ex, jj, 64);
                    if (v <= pos) j = jj;
                }
                unsigned cand = min(pos + __shfl(dif, j, 64), (unsigned)(NPTS - 1));
                bool in = pos < T;
                float4 c = sp[cand];
                float dx = qx - c.x, dy = qy - c.y, dz = qz - c.z;
                float d2 = dx * dx + dy * dy + dz * dz;   // reference-form d2
                bool pass = in && (d2 < g2);
                unsigned long long m = __ballot(pass);
                if (pass) {
                    unsigned slot = min(cnt + mbcnt64(m), (unsigned)(SSTRIDE - 1));
                    survk[sbase + slot] = mkkey(d2, __float_as_uint(c.w));
                }
                cnt += (unsigned)__popcll(m);
            }
        }
        if (lane == 0) cnts[q] = cnt;
    }
    __syncthreads();   // B1

    // ---- Phase B: 4 lanes per query ----
    const int qq = lane >> 2;            // query within half 0..15
    const int h = lane & 3;              // sub-lane
    const int myq = (w & 1) * 16 + qq;   // query 0..31
    float4 qv = pbuf4[eighth * NQ + myq];
    const float pqx = qv.x, pqy = qv.y, pqz = qv.z;

    double ngx = 0, ngy = 0, ngz = 0, svg = 0;

    if (w < 2) {
        // Global top-16: split survivor keys 4 ways, gated bubble, butterfly merge.
        unsigned gl[KNN];
        #pragma unroll
        for (int m = 0; m < KNN; ++m) gl[m] = 0xFFFFFFFFu;
        unsigned cnt = cnts[myq];
        bool valid = (cnt >= KNN) && (cnt <= SSTRIDE);
        if (valid) {
            unsigned share = (cnt + 3) >> 2;
            unsigned m0 = h * share;
            unsigned m1 = min(m0 + share, cnt);
            #pragma unroll 1
            for (unsigned m = m0; m < m1; ++m) {
                unsigned k = survk[myq * SSTRIDE + m];
                if (k < gl[KNN - 1]) insert16(k, gl);
            }
        }
        merge4(gl, lane);
        if (valid) {
            // margin check: all filtered-out points provably outside 16th bucket
            float g = gbuf[myq];
            float upper = __uint_as_float((gl[KNN - 1] & 0xFFFFE000u) + 0x2000u);
            valid = (upper < g * 0.999f - 1e-5f);
        }
        if (__any((h == 0 && !valid) ? 1 : 0)) {
            if (h == 0 && !valid) {   // exact fallback (P ~ 1e-9/query)
                #pragma unroll
                for (int m = 0; m < KNN; ++m) gl[m] = 0xFFFFFFFFu;
                #pragma unroll 1
                for (int i = 0; i < NPTS; ++i) {
                    float cx = base[i * 3 + 0];
                    float cy = base[i * 3 + 1];
                    float cz = base[i * 3 + 2];
                    float dx = pqx - cx, dy = pqy - cy, dz = pqz - cz;
                    float d2 = dx * dx + dy * dy + dz * dz;
                    unsigned k = mkkey(d2, (unsigned)i);
                    if (k < gl[KNN - 1]) insert16(k, gl);
                }
            }
        }
        if (h == 0) {
            double c00 = 0, c11 = 0, c22 = 0, c01 = 0, c02 = 0, c12 = 0;
            const double qxd = pqx, qyd = pqy, qzd = pqz;
            #pragma unroll
            for (int m = 0; m < KNN; ++m) {
                int idx = (int)(gl[m] & 0x1FFFu);
                double dx = (double)base[idx * 3 + 0] - qxd;
                double dy = (double)base[idx * 3 + 1] - qyd;
                double dz = (double)base[idx * 3 + 2] - qzd;
                c00 += dx * dx; c11 += dy * dy; c22 += dz * dz;
                c01 += dx * dy; c02 += dx * dz; c12 += dy * dz;
            }
            double lmin, lsum;
            eig3(c00, c11, c22, c01, c02, c12, ngx, ngy, ngz, lmin, lsum);
            svg = lmin / lsum;
        }
    } else {
        // Patch kNN: 4 lanes x 64 patch points, gated bubble, butterfly merge.
        unsigned pl[KNN];
        #pragma unroll
        for (int m = 0; m < KNN; ++m) pl[m] = 0xFFFFFFFFu;
        const int j0 = h * 64;
        #pragma unroll 1
        for (int j = j0; j < j0 + 64; ++j) {
            float4 c = pbuf4[j];
            float dx = pqx - c.x, dy = pqy - c.y, dz = pqz - c.z;
            float d2 = dx * dx + dy * dy + dz * dz;
            unsigned k = mkkey(d2, (unsigned)j);
            if (k < pl[KNN - 1]) insert16(k, pl);
        }
        merge4(pl, lane);
        if (h == 0) {
            double c00 = 0, c11 = 0, c22 = 0, c01 = 0, c02 = 0, c12 = 0;
            const double qxd = pqx, qyd = pqy, qzd = pqz;
            #pragma unroll
            for (int m = 0; m < KNN; ++m) {
                int idx = (int)(pl[m] & 0x1FFFu);
                float4 cpt = pbuf4[idx];
                double dx = (double)cpt.x - qxd;
                double dy = (double)cpt.y - qyd;
                double dz = (double)cpt.z - qzd;
                c00 += dx * dx; c11 += dy * dy; c22 += dz * dz;
                c01 += dx * dy; c02 += dx * dz; c12 += dy * dz;
            }
            double nx, ny, nz, lmin, lsum;
            eig3(c00, c11, c22, c01, c02, c12, nx, ny, nz, lmin, lsum);
            xbuf[myq * 4 + 0] = nx;
            xbuf[myq * 4 + 1] = ny;
            xbuf[myq * 4 + 2] = nz;
            xbuf[myq * 4 + 3] = lmin / lsum;
        }
    }
    __syncthreads();   // B2

    double ln = 0.0, lsv = 0.0;
    if (w < 2 && h == 0) {
        double npx = xbuf[myq * 4 + 0];
        double npy = xbuf[myq * 4 + 1];
        double npz = xbuf[myq * 4 + 2];
        double svp = xbuf[myq * 4 + 3];
        double dx = fabs(npx) - fabs(ngx);
        double dy = fabs(npy) - fabs(ngy);
        double dz = fabs(npz) - fabs(ngz);
        ln  = sqrt(dx * dx + dy * dy + dz * dz);
        double ds = svp - svg;
        lsv = ds * ds;
    }
    if (w < 2) {
        #pragma unroll
        for (int o = 32; o > 0; o >>= 1) {
            ln  += __shfl_down(ln, o);
            lsv += __shfl_down(lsv, o);
        }
        if (lane == 0) { rb[w * 2 + 0] = ln; rb[w * 2 + 1] = lsv; }
    }
    __syncthreads();   // B3
    if (t == 0) {
        const double inv = 1.0 / (double)(NBATCH * NPTS);
        atomicAdd(&out[0], (float)((rb[0] + rb[2]) * inv));
        atomicAdd(&out[1], (float)((rb[1] + rb[3]) * inv));
    }
}

extern "C" void kernel_launch(void* const* d_in, const int* in_sizes, int n_in,
                              void* d_out, int out_size, void* d_ws, size_t ws_size,
                              hipStream_t stream)
{
    const float* pts = (const float*)d_in[0];
    float* out = (float*)d_out;

    // workspace carve-up (16B-aligned): ~590 KB total
    unsigned char* ws = (unsigned char*)d_ws;
    unsigned* cellStart = (unsigned*)(ws);            // 4*4097*4 = 65552 B
    float4*   sorted    = (float4*)  (ws + 65552);    // 4*8192*16 = 524288 B

    hipLaunchKernelGGL(build_kernel, dim3(NBATCH), dim3(BT), 0, stream,
                       pts, out, cellStart, sorted);
    dim3 grid(NPATCH, 8, NBATCH);
    hipLaunchKernelGGL(spl_main, grid, dim3(256), 0, stream, pts, out, cellStart, sorted);
}